// Round 1
// baseline (9153.758 us; speedup 1.0000x reference)
//
#include <hip/hip_runtime.h>

#define BB 256
#define LL 128
#define HH 512
#define H4 2048

typedef unsigned short us;
typedef __attribute__((ext_vector_type(8))) __bf16 bf16x8;
typedef __attribute__((ext_vector_type(4))) float f32x4;

__device__ __forceinline__ float bf2f(us s) {
    unsigned u = ((unsigned)s) << 16;
    return __builtin_bit_cast(float, u);
}
__device__ __forceinline__ us f2bf(float f) {
    unsigned u = __builtin_bit_cast(unsigned, f);
    return (us)((u + 0x7fffu + ((u >> 16) & 1u)) >> 16);
}
__device__ __forceinline__ float sigm(float x) { return 1.f / (1.f + __expf(-x)); }
__device__ __forceinline__ float tanh_(float x) { return 1.f - 2.f / (1.f + __expf(2.f * x)); }
__device__ __forceinline__ bf16x8 ldb8(const us* p) { return *(const bf16x8*)(const void*)p; }

// ---- group/grid barrier: flag per block (64B padded), relaxed polls + one fence pair ----
// myidx: this block's flat flag index; polls flags [base, base+n).
__device__ __forceinline__ void gsync(unsigned* flags, int myidx, int base, int n, unsigned target) {
    __syncthreads();
    if (threadIdx.x < 64) {
        if (threadIdx.x == 0) {
            __builtin_amdgcn_fence(__ATOMIC_RELEASE, "agent");
            __hip_atomic_store(flags + (size_t)myidx * 16, target, __ATOMIC_RELAXED,
                               __HIP_MEMORY_SCOPE_AGENT);
        }
        for (int i = (int)threadIdx.x; i < n; i += 64)
            while (__hip_atomic_load(flags + (size_t)(base + i) * 16, __ATOMIC_RELAXED,
                                     __HIP_MEMORY_SCOPE_AGENT) < target) {}
        __builtin_amdgcn_fence(__ATOMIC_ACQUIRE, "agent");
    }
    __syncthreads();
}

// One persistent cooperative kernel: converts -> encoder loop -> enc_w1 GEMM -> decoder loop.
// grid 256 blocks x 512 threads (1 block/CU). Group = 16 blocks sharing (blockIdx & 15),
// handling batches g*16..g*16+15. All recurrent data flow is group-local -> 16-wide barriers.
extern "C" __global__ void __launch_bounds__(512) k_mega(
    const int* __restrict__ xs, const int* __restrict__ argsort,
    const float* __restrict__ enc_Wi, const float* __restrict__ enc_Wh, const float* __restrict__ enc_b,
    const float* __restrict__ dec_Wi, const float* __restrict__ dec_Wh, const float* __restrict__ dec_b,
    const float* __restrict__ w1, const float* __restrict__ w2, const float* __restrict__ vt,
    float* __restrict__ out, char* __restrict__ ws) {
    // workspace layout (flags live in the old c_ws region; c-state is in registers now)
    unsigned* flags = (unsigned*)ws;             // 256 * 64B = 16384
    float* din = (float*)(ws + 524288);          // 2*256*4
    us* hdec = (us*)(ws + 526336);               // 2*256*512*2
    us* q = (us*)(ws + 1050624);                 // 256*512*2
    us* ctx = (us*)(ws + 1312768);               // 256*512*2
    us* wiR = (us*)(ws + 1574912);               // 2048*512*2
    float* wi_last = (float*)(ws + 3672064);     // 2048*4
    us* whE = (us*)(ws + 3680256);               // 2048*512*2
    us* whD = (us*)(ws + 5777408);               // 2048*512*2
    us* w1B = (us*)(ws + 7874560);               // 512*512*2
    us* w2B = (us*)(ws + 8398848);               // 512*512*2
    us* enc_out = (us*)(ws + 8923136);           // 256*128*512*2
    us* enc_w1 = (us*)(ws + 42477568);           // 256*128*512*2

    __shared__ float scs[LL];
    __shared__ float aj[LL];
    __shared__ float redm[2];
    __shared__ float reds[2];

    const int tid = threadIdx.x;
    const int lane = tid & 63;
    const int w = tid >> 6;                      // wave 0..7
    const int l15 = lane & 15, quad = lane >> 4;
    const int blk = blockIdx.x;
    const int g = blk & 15;                      // group id (batch-tile)
    const int m = blk >> 4;                      // member 0..15
    const int b0 = g << 4;                       // batch base of group
    const int myflag = g * 16 + m;
    unsigned tgt = 0;

    // ---------------- phase C: weight converts (striped across all 131072 threads) ----------------
    {
        int gt = blk * 512 + tid;
        for (int i = gt; i < H4 * HH; i += 131072) whE[i] = f2bf(enc_Wh[i]);
        for (int i = gt; i < H4 * HH; i += 131072) whD[i] = f2bf(dec_Wh[i]);
        for (int i = gt; i < HH * HH; i += 131072) w1B[i] = f2bf(w1[i]);
        for (int i = gt; i < HH * HH; i += 131072) w2B[i] = f2bf(w2[i]);
        for (int i = gt; i < H4 * HH; i += 131072)
            wiR[i] = f2bf(dec_Wi[(size_t)(i >> 9) * 513 + (i & 511)]);
        if (gt < H4) wi_last[gt] = dec_Wi[(size_t)gt * 513 + 512];
    }
    gsync(flags, myflag, 0, 256, ++tgt);  // full barrier: weights feed every group

    // wave's column tile (valid for w<2): c0 in {0,16,...,496}
    const int c0 = ((m << 1) | (w & 1)) << 4;
    float creg[4] = {0.f, 0.f, 0.f, 0.f};  // LSTM cell state, persists encoder -> decoder

    // ---------------- encoder: 128 steps, 1 group barrier each ----------------
    float biE[4], wiE[4];
    if (w < 2) {
#pragma unroll
        for (int gg = 0; gg < 4; ++gg) {
            int rg = gg * HH + c0 + l15;
            biE[gg] = enc_b[rg];
            wiE[gg] = enc_Wi[rg];
        }
    }
    for (int t = 0; t < LL; ++t) {
        if (w < 2) {
            f32x4 acc[4] = {};
            if (t > 0) {
                const us* Ar = enc_out + ((size_t)(b0 + l15) * LL + (t - 1)) * HH + quad * 8;
                const us* Br = whE + (size_t)(c0 + l15) * HH + quad * 8;
#pragma unroll 4
                for (int kk = 0; kk < 16; ++kk) {
                    bf16x8 a = ldb8(Ar + kk * 32);
#pragma unroll
                    for (int gg = 0; gg < 4; ++gg) {
                        bf16x8 bv = ldb8(Br + (size_t)gg * HH * HH + kk * 32);
                        acc[gg] = __builtin_amdgcn_mfma_f32_16x16x32_bf16(a, bv, acc[gg], 0, 0, 0);
                    }
                }
            }
#pragma unroll
            for (int r = 0; r < 4; ++r) {
                int b = b0 + quad * 4 + r;
                float xv = (float)xs[b * LL + t];
                float zi = acc[0][r] + biE[0] + xv * wiE[0];
                float zf = acc[1][r] + biE[1] + xv * wiE[1];
                float zg = acc[2][r] + biE[2] + xv * wiE[2];
                float zo = acc[3][r] + biE[3] + xv * wiE[3];
                float c_ = sigm(zf) * creg[r] + sigm(zi) * tanh_(zg);
                creg[r] = c_;
                us hb = f2bf(sigm(zo) * tanh_(c_));
                enc_out[((size_t)b * LL + t) * HH + c0 + l15] = hb;
                if (t == LL - 1) hdec[(size_t)b * HH + c0 + l15] = hb;
            }
        }
        gsync(flags, myflag, g * 16, 16, ++tgt);
    }

    // ---------------- enc_w1 = enc_out @ w1^T (group-local rows, all 8 waves) ----------------
    {
        int lw = m * 8 + w;  // 0..127 local wave id within group
        for (int it = 0; it < 8; ++it) {
            int task = it * 128 + lw;            // 1024 tasks: 128 m-tiles x 8 n-groups
            int mt = task >> 3;
            int n0 = (task & 7) << 6;
            size_t m0 = (size_t)b0 * LL + (size_t)mt * 16;
            f32x4 acc[4] = {};
            const us* Ar = enc_out + (m0 + l15) * HH + quad * 8;
            const us* Br = w1B + (size_t)(n0 + l15) * HH + quad * 8;
#pragma unroll 4
            for (int kk = 0; kk < 16; ++kk) {
                bf16x8 a = ldb8(Ar + kk * 32);
#pragma unroll
                for (int tt = 0; tt < 4; ++tt) {
                    bf16x8 bv = ldb8(Br + (size_t)tt * 16 * HH + kk * 32);
                    acc[tt] = __builtin_amdgcn_mfma_f32_16x16x32_bf16(a, bv, acc[tt], 0, 0, 0);
                }
            }
#pragma unroll
            for (int tt = 0; tt < 4; ++tt)
#pragma unroll
                for (int r = 0; r < 4; ++r)
                    enc_w1[(m0 + quad * 4 + r) * HH + n0 + tt * 16 + l15] = f2bf(acc[tt][r]);
        }
    }
    gsync(flags, myflag, g * 16, 16, ++tgt);

    // ---------------- decoder: 128 steps, 3 group barriers each ----------------
    float biD[4], wlD[4];
    if (w < 2) {
#pragma unroll
        for (int gg = 0; gg < 4; ++gg) {
            int rg = gg * HH + c0 + l15;
            biD[gg] = dec_b[rg];
            wlD[gg] = wi_last[rg];
        }
    }
    for (int t = 0; t < LL; ++t) {
        const us* hcur = hdec + (size_t)(t & 1) * BB * HH;

        // ---- Q: q = h @ w2^T, 32 n-tiles over waves w<2 ----
        if (w < 2) {
            f32x4 acc = {};
            const us* Ar = hcur + (size_t)(b0 + l15) * HH + quad * 8;
            const us* Br = w2B + (size_t)(c0 + l15) * HH + quad * 8;
#pragma unroll 4
            for (int kk = 0; kk < 16; ++kk) {
                bf16x8 a = ldb8(Ar + kk * 32);
                bf16x8 bv = ldb8(Br + kk * 32);
                acc = __builtin_amdgcn_mfma_f32_16x16x32_bf16(a, bv, acc, 0, 0, 0);
            }
#pragma unroll
            for (int r = 0; r < 4; ++r)
                q[(size_t)(b0 + quad * 4 + r) * HH + c0 + l15] = f2bf(acc[r]);
        }
        gsync(flags, myflag, g * 16, 16, ++tgt);

        // ---- A: attention for batch b0+m (all 512 threads) ----
        {
            int b = b0 + m;
            int k0 = lane * 8;
            bf16x8 qv = ldb8(q + (size_t)b * HH + k0);
            float qk[8], vtk[8];
#pragma unroll
            for (int j = 0; j < 8; ++j) {
                qk[j] = (float)qv[j];
                vtk[j] = vt[k0 + j];
            }
            const us* wbase = enc_w1 + (size_t)b * LL * HH + k0;
#pragma unroll 4
            for (int i = 0; i < 16; ++i) {
                int l = i * 8 + w;
                bf16x8 e8 = ldb8(wbase + (size_t)l * HH);
                float s = 0.f;
#pragma unroll
                for (int j = 0; j < 8; ++j) s += tanh_((float)e8[j] + qk[j]) * vtk[j];
#pragma unroll
                for (int off = 1; off < 64; off <<= 1) s += __shfl_xor(s, off);
                if (lane == 0) scs[l] = s;
            }
            __syncthreads();
            bool act = tid < 128;
            float sc = act ? scs[tid] : -1e30f;
            float mx = sc;
#pragma unroll
            for (int off = 1; off < 64; off <<= 1) mx = fmaxf(mx, __shfl_xor(mx, off));
            if (act && lane == 0) redm[w] = mx;
            __syncthreads();
            float M = fmaxf(redm[0], redm[1]);
            float e = act ? __expf(sc - M) : 0.f;
            float ss = e;
#pragma unroll
            for (int off = 1; off < 64; off <<= 1) ss += __shfl_xor(ss, off);
            if (act && lane == 0) reds[w] = ss;
            __syncthreads();
            float S = reds[0] + reds[1];
            if (act) {
                out[((size_t)b * LL + t) * LL + tid] = sc - M - __logf(S);
                aj[tid] = e / S;
            }
            __syncthreads();
            const us* ep = enc_out + (size_t)b * LL * HH + tid;
            float cacc = 0.f;
#pragma unroll 8
            for (int l2 = 0; l2 < LL; ++l2) cacc += aj[l2] * bf2f(ep[(size_t)l2 * HH]);
            ctx[(size_t)b * HH + tid] = f2bf(cacc);
            if (tid == 0) {
                int idx = argsort[b * LL + t];
                din[(size_t)((t + 1) & 1) * BB + b] = (float)xs[b * LL + idx];
            }
        }
        gsync(flags, myflag, g * 16, 16, ++tgt);

        // ---- Z: z = [ctx|h] @ W^T + b ; gates -> h_{t+1}, c in regs ----
        if (w < 2) {
            f32x4 acc[4] = {};
            const us* A1 = ctx + (size_t)(b0 + l15) * HH + quad * 8;
            const us* B1 = wiR + (size_t)(c0 + l15) * HH + quad * 8;
#pragma unroll 4
            for (int kk = 0; kk < 16; ++kk) {
                bf16x8 a = ldb8(A1 + kk * 32);
#pragma unroll
                for (int gg = 0; gg < 4; ++gg) {
                    bf16x8 bv = ldb8(B1 + (size_t)gg * HH * HH + kk * 32);
                    acc[gg] = __builtin_amdgcn_mfma_f32_16x16x32_bf16(a, bv, acc[gg], 0, 0, 0);
                }
            }
            const us* A2 = hcur + (size_t)(b0 + l15) * HH + quad * 8;
            const us* B2 = whD + (size_t)(c0 + l15) * HH + quad * 8;
#pragma unroll 4
            for (int kk = 0; kk < 16; ++kk) {
                bf16x8 a = ldb8(A2 + kk * 32);
#pragma unroll
                for (int gg = 0; gg < 4; ++gg) {
                    bf16x8 bv = ldb8(B2 + (size_t)gg * HH * HH + kk * 32);
                    acc[gg] = __builtin_amdgcn_mfma_f32_16x16x32_bf16(a, bv, acc[gg], 0, 0, 0);
                }
            }
            us* hnxt = hdec + (size_t)((t + 1) & 1) * BB * HH;
            const float* dcur = din + (size_t)(t & 1) * BB;
#pragma unroll
            for (int r = 0; r < 4; ++r) {
                int b = b0 + quad * 4 + r;
                float dv = (t == 0) ? 0.f : dcur[b];
                float zi = acc[0][r] + biD[0] + dv * wlD[0];
                float zf = acc[1][r] + biD[1] + dv * wlD[1];
                float zg = acc[2][r] + biD[2] + dv * wlD[2];
                float zo = acc[3][r] + biD[3] + dv * wlD[3];
                float c_ = sigm(zf) * creg[r] + sigm(zi) * tanh_(zg);
                creg[r] = c_;
                hnxt[(size_t)b * HH + c0 + l15] = f2bf(sigm(zo) * tanh_(c_));
            }
        }
        gsync(flags, myflag, g * 16, 16, ++tgt);
    }
}

extern "C" void kernel_launch(void* const* d_in, const int* in_sizes, int n_in,
                              void* d_out, int out_size, void* d_ws, size_t ws_size,
                              hipStream_t stream) {
    const int* xs = (const int*)d_in[0];
    const int* argsort = (const int*)d_in[2];
    const float* enc_Wi = (const float*)d_in[3];
    const float* enc_Wh = (const float*)d_in[4];
    const float* enc_b = (const float*)d_in[5];
    const float* dec_Wi = (const float*)d_in[6];
    const float* dec_Wh = (const float*)d_in[7];
    const float* dec_b = (const float*)d_in[8];
    const float* w1 = (const float*)d_in[9];
    const float* w2 = (const float*)d_in[10];
    const float* vt = (const float*)d_in[11];
    float* out = (float*)d_out;
    char* ws = (char*)d_ws;

    // zero barrier flags (ws is re-poisoned each launch; targets are absolute)
    hipMemsetAsync(ws, 0, 16384, stream);

    void* kargs[] = {&xs, &argsort, &enc_Wi, &enc_Wh, &enc_b, &dec_Wi, &dec_Wh, &dec_b,
                     &w1, &w2, &vt, &out, &ws};
    hipLaunchCooperativeKernel((void*)k_mega, dim3(256), dim3(512), kargs, 0, stream);

    (void)in_sizes; (void)n_in; (void)out_size; (void)ws_size;
}

// Round 2
// 6996.313 us; speedup vs baseline: 1.3084x; 1.3084x over previous
//
#include <hip/hip_runtime.h>

#define BB 256
#define LL 128
#define HH 512
#define H4 2048

typedef unsigned short us;
typedef unsigned long long u64;
typedef __attribute__((ext_vector_type(8))) __bf16 bf16x8;
typedef __attribute__((ext_vector_type(4))) float f32x4;

__device__ __forceinline__ float bf2f(us s) {
    unsigned u = ((unsigned)s) << 16;
    return __builtin_bit_cast(float, u);
}
__device__ __forceinline__ us f2bf(float f) {
    unsigned u = __builtin_bit_cast(unsigned, f);
    return (us)((u + 0x7fffu + ((u >> 16) & 1u)) >> 16);
}
__device__ __forceinline__ float sigm(float x) { return 1.f / (1.f + __expf(-x)); }
__device__ __forceinline__ float tanh_(float x) { return 1.f - 2.f / (1.f + __expf(2.f * x)); }
__device__ __forceinline__ bf16x8 ldb8(const us* p) { return *(const bf16x8*)(const void*)p; }

// ---- device-coherent (L2-bypassing) accessors for cross-block recurrent data ----
// relaxed agent-scope atomics compile to sc1 (device-scope) loads/stores: coherent at MALL,
// no cache-maintenance fences needed.
__device__ __forceinline__ bf16x8 ldb8_dev(const us* p) {
    union { u64 q[2]; bf16x8 v; } u;
    u.q[0] = __hip_atomic_load((const u64*)(const void*)p, __ATOMIC_RELAXED, __HIP_MEMORY_SCOPE_AGENT);
    u.q[1] = __hip_atomic_load((const u64*)(const void*)p + 1, __ATOMIC_RELAXED, __HIP_MEMORY_SCOPE_AGENT);
    return u.v;
}
// lanes (2i,2i+1) hold adjacent bf16 columns of the same row: even lane stores packed 4B
__device__ __forceinline__ void st_pair_dev(us* p, unsigned myv, int lane) {
    unsigned ov = __shfl_xor(myv, 1);
    if (!(lane & 1)) {
        unsigned pk = (myv & 0xffffu) | (ov << 16);
        __hip_atomic_store((unsigned*)(void*)p, pk, __ATOMIC_RELAXED, __HIP_MEMORY_SCOPE_AGENT);
    }
}

// ---- fence-free group barrier: syncthreads drains vmcnt (bypassing stores are then
// globally visible) -> relaxed flag store -> relaxed poll. NO L2 writeback/invalidate. ----
__device__ __forceinline__ void gsync_nf(unsigned* flags, int myidx, int base, int n, unsigned target) {
    __syncthreads();  // all waves arrived; compiler drains vmcnt(0) per-wave before s_barrier
    if (threadIdx.x < 64) {
        if (threadIdx.x == 0)
            __hip_atomic_store(flags + (size_t)myidx * 16, target, __ATOMIC_RELAXED,
                               __HIP_MEMORY_SCOPE_AGENT);
        for (int i = (int)threadIdx.x; i < n; i += 64)
            while (__hip_atomic_load(flags + (size_t)(base + i) * 16, __ATOMIC_RELAXED,
                                     __HIP_MEMORY_SCOPE_AGENT) < target) {}
        asm volatile("" ::: "memory");
    }
    __syncthreads();
}

// ---- fenced barrier (L2 wb + inv) — used exactly TWICE (after converts, after enc_w1) ----
__device__ __forceinline__ void gsync_f(unsigned* flags, int myidx, int base, int n, unsigned target) {
    __syncthreads();
    if (threadIdx.x < 64) {
        if (threadIdx.x == 0) {
            __builtin_amdgcn_fence(__ATOMIC_RELEASE, "agent");
            __hip_atomic_store(flags + (size_t)myidx * 16, target, __ATOMIC_RELAXED,
                               __HIP_MEMORY_SCOPE_AGENT);
        }
        for (int i = (int)threadIdx.x; i < n; i += 64)
            while (__hip_atomic_load(flags + (size_t)(base + i) * 16, __ATOMIC_RELAXED,
                                     __HIP_MEMORY_SCOPE_AGENT) < target) {}
        __builtin_amdgcn_fence(__ATOMIC_ACQUIRE, "agent");
    }
    __syncthreads();
}

// One persistent cooperative kernel. Group = 16 blocks sharing (blockIdx & 15), batches
// g*16..g*16+15. Cross-block recurrent buffers (hdec,q,ctx,din, flag array) are accessed
// ONLY via L2-bypassing atomics; weights and write-once tensors stay L2-cached.
extern "C" __global__ void __launch_bounds__(512) k_mega(
    const int* __restrict__ xs, const int* __restrict__ argsort,
    const float* __restrict__ enc_Wi, const float* __restrict__ enc_Wh, const float* __restrict__ enc_b,
    const float* __restrict__ dec_Wi, const float* __restrict__ dec_Wh, const float* __restrict__ dec_b,
    const float* __restrict__ w1, const float* __restrict__ w2, const float* __restrict__ vt,
    float* __restrict__ out, char* __restrict__ ws) {
    unsigned* flags = (unsigned*)ws;             // 256 * 64B = 16384
    float* din = (float*)(ws + 524288);          // 2*256*4
    us* hdec = (us*)(ws + 526336);               // 2*256*512*2
    us* q = (us*)(ws + 1050624);                 // 256*512*2
    us* ctx = (us*)(ws + 1312768);               // 256*512*2
    us* wiR = (us*)(ws + 1574912);               // 2048*512*2
    float* wi_last = (float*)(ws + 3672064);     // 2048*4
    us* whE = (us*)(ws + 3680256);               // 2048*512*2
    us* whD = (us*)(ws + 5777408);               // 2048*512*2
    us* w1B = (us*)(ws + 7874560);               // 512*512*2
    us* w2B = (us*)(ws + 8398848);               // 512*512*2
    us* enc_out = (us*)(ws + 8923136);           // 256*128*512*2
    us* enc_w1 = (us*)(ws + 42477568);           // 256*128*512*2

    __shared__ float scs[LL];
    __shared__ float aj[LL];
    __shared__ float redm[2];
    __shared__ float reds[2];

    const int tid = threadIdx.x;
    const int lane = tid & 63;
    const int w = tid >> 6;
    const int l15 = lane & 15, quad = lane >> 4;
    const int blk = blockIdx.x;
    const int g = blk & 15;
    const int m = blk >> 4;
    const int b0 = g << 4;
    const int myflag = g * 16 + m;
    unsigned tgt = 0;

    // ---------------- weight converts (cached stores; one fenced barrier publishes) ----------------
    {
        int gt = blk * 512 + tid;
        for (int i = gt; i < H4 * HH; i += 131072) whE[i] = f2bf(enc_Wh[i]);
        for (int i = gt; i < H4 * HH; i += 131072) whD[i] = f2bf(dec_Wh[i]);
        for (int i = gt; i < HH * HH; i += 131072) w1B[i] = f2bf(w1[i]);
        for (int i = gt; i < HH * HH; i += 131072) w2B[i] = f2bf(w2[i]);
        for (int i = gt; i < H4 * HH; i += 131072)
            wiR[i] = f2bf(dec_Wi[(size_t)(i >> 9) * 513 + (i & 511)]);
        if (gt < H4) wi_last[gt] = dec_Wi[(size_t)gt * 513 + 512];
    }
    gsync_f(flags, myflag, 0, 256, ++tgt);

    const int c0 = ((m << 1) | (w & 1)) << 4;
    float creg[4] = {0.f, 0.f, 0.f, 0.f};

    // ---------------- encoder: 128 steps, fence-free group barriers ----------------
    float biE[4], wiE[4];
    if (w < 2) {
#pragma unroll
        for (int gg = 0; gg < 4; ++gg) {
            int rg = gg * HH + c0 + l15;
            biE[gg] = enc_b[rg];
            wiE[gg] = enc_Wi[rg];
        }
    }
    for (int t = 0; t < LL; ++t) {
        if (w < 2) {
            f32x4 acc[4] = {};
            if (t > 0) {
                // enc_out slice t-1: bypass-written once, cached read misses -> fresh from MALL
                const us* Ar = enc_out + ((size_t)(b0 + l15) * LL + (t - 1)) * HH + quad * 8;
                const us* Br = whE + (size_t)(c0 + l15) * HH + quad * 8;
#pragma unroll 4
                for (int kk = 0; kk < 16; ++kk) {
                    bf16x8 a = ldb8(Ar + kk * 32);
#pragma unroll
                    for (int gg = 0; gg < 4; ++gg) {
                        bf16x8 bv = ldb8(Br + (size_t)gg * HH * HH + kk * 32);
                        acc[gg] = __builtin_amdgcn_mfma_f32_16x16x32_bf16(a, bv, acc[gg], 0, 0, 0);
                    }
                }
            }
#pragma unroll
            for (int r = 0; r < 4; ++r) {
                int b = b0 + quad * 4 + r;
                float xv = (float)xs[b * LL + t];
                float zi = acc[0][r] + biE[0] + xv * wiE[0];
                float zf = acc[1][r] + biE[1] + xv * wiE[1];
                float zg = acc[2][r] + biE[2] + xv * wiE[2];
                float zo = acc[3][r] + biE[3] + xv * wiE[3];
                float c_ = sigm(zf) * creg[r] + sigm(zi) * tanh_(zg);
                creg[r] = c_;
                unsigned hv = (unsigned)f2bf(sigm(zo) * tanh_(c_));
                st_pair_dev(&enc_out[((size_t)b * LL + t) * HH + c0 + l15], hv, lane);
                if (t == LL - 1) st_pair_dev(&hdec[(size_t)b * HH + c0 + l15], hv, lane);
            }
        }
        gsync_nf(flags, myflag, g * 16, 16, ++tgt);
    }

    // ---------------- enc_w1 = enc_out @ w1^T (cached writes; fenced barrier publishes) ----------------
    {
        int lw = m * 8 + w;
        for (int it = 0; it < 8; ++it) {
            int task = it * 128 + lw;
            int mt = task >> 3;
            int n0 = (task & 7) << 6;
            size_t m0 = (size_t)b0 * LL + (size_t)mt * 16;
            f32x4 acc[4] = {};
            const us* Ar = enc_out + (m0 + l15) * HH + quad * 8;
            const us* Br = w1B + (size_t)(n0 + l15) * HH + quad * 8;
#pragma unroll 4
            for (int kk = 0; kk < 16; ++kk) {
                bf16x8 a = ldb8(Ar + kk * 32);
#pragma unroll
                for (int tt = 0; tt < 4; ++tt) {
                    bf16x8 bv = ldb8(Br + (size_t)tt * 16 * HH + kk * 32);
                    acc[tt] = __builtin_amdgcn_mfma_f32_16x16x32_bf16(a, bv, acc[tt], 0, 0, 0);
                }
            }
#pragma unroll
            for (int tt = 0; tt < 4; ++tt)
#pragma unroll
                for (int r = 0; r < 4; ++r)
                    enc_w1[(m0 + quad * 4 + r) * HH + n0 + tt * 16 + l15] = f2bf(acc[tt][r]);
        }
    }
    gsync_f(flags, myflag, g * 16, 16, ++tgt);

    // ---------------- decoder: 128 steps, 3 fence-free group barriers each ----------------
    float biD[4], wlD[4];
    if (w < 2) {
#pragma unroll
        for (int gg = 0; gg < 4; ++gg) {
            int rg = gg * HH + c0 + l15;
            biD[gg] = dec_b[rg];
            wlD[gg] = wi_last[rg];
        }
    }
    for (int t = 0; t < LL; ++t) {
        const us* hcur = hdec + (size_t)(t & 1) * BB * HH;

        // ---- Q: q = h @ w2^T ----
        if (w < 2) {
            f32x4 acc = {};
            const us* Ar = hcur + (size_t)(b0 + l15) * HH + quad * 8;
            const us* Br = w2B + (size_t)(c0 + l15) * HH + quad * 8;
#pragma unroll 4
            for (int kk = 0; kk < 16; ++kk) {
                bf16x8 a = ldb8_dev(Ar + kk * 32);
                bf16x8 bv = ldb8(Br + kk * 32);
                acc = __builtin_amdgcn_mfma_f32_16x16x32_bf16(a, bv, acc, 0, 0, 0);
            }
#pragma unroll
            for (int r = 0; r < 4; ++r)
                st_pair_dev(&q[(size_t)(b0 + quad * 4 + r) * HH + c0 + l15],
                            (unsigned)f2bf(acc[r]), lane);
        }
        gsync_nf(flags, myflag, g * 16, 16, ++tgt);

        // ---- A: attention for batch b0+m ----
        {
            int b = b0 + m;
            int k0 = lane * 8;
            bf16x8 qv = ldb8_dev(q + (size_t)b * HH + k0);
            float qk[8], vtk[8];
#pragma unroll
            for (int j = 0; j < 8; ++j) {
                qk[j] = (float)qv[j];
                vtk[j] = vt[k0 + j];
            }
            const us* wbase = enc_w1 + (size_t)b * LL * HH + k0;
#pragma unroll 4
            for (int i = 0; i < 16; ++i) {
                int l = i * 8 + w;
                bf16x8 e8 = ldb8(wbase + (size_t)l * HH);
                float s = 0.f;
#pragma unroll
                for (int j = 0; j < 8; ++j) s += tanh_((float)e8[j] + qk[j]) * vtk[j];
#pragma unroll
                for (int off = 1; off < 64; off <<= 1) s += __shfl_xor(s, off);
                if (lane == 0) scs[l] = s;
            }
            __syncthreads();
            bool act = tid < 128;
            float sc = act ? scs[tid] : -1e30f;
            float mx = sc;
#pragma unroll
            for (int off = 1; off < 64; off <<= 1) mx = fmaxf(mx, __shfl_xor(mx, off));
            if (act && lane == 0) redm[w] = mx;
            __syncthreads();
            float M = fmaxf(redm[0], redm[1]);
            float e = act ? __expf(sc - M) : 0.f;
            float ss = e;
#pragma unroll
            for (int off = 1; off < 64; off <<= 1) ss += __shfl_xor(ss, off);
            if (act && lane == 0) reds[w] = ss;
            __syncthreads();
            float S = reds[0] + reds[1];
            if (act) {
                out[((size_t)b * LL + t) * LL + tid] = sc - M - __logf(S);
                aj[tid] = e / S;
            }
            __syncthreads();
            const us* ep = enc_out + (size_t)b * LL * HH + tid;
            float cacc = 0.f;
#pragma unroll 8
            for (int l2 = 0; l2 < LL; ++l2) cacc += aj[l2] * bf2f(ep[(size_t)l2 * HH]);
            st_pair_dev(&ctx[(size_t)b * HH + tid], (unsigned)f2bf(cacc), tid & 63);
            if (tid == 0) {
                int idx = argsort[b * LL + t];
                __hip_atomic_store(&din[(size_t)((t + 1) & 1) * BB + b], (float)xs[b * LL + idx],
                                   __ATOMIC_RELAXED, __HIP_MEMORY_SCOPE_AGENT);
            }
        }
        gsync_nf(flags, myflag, g * 16, 16, ++tgt);

        // ---- Z: z = [ctx|h] @ W^T + b ; gates -> h_{t+1} ----
        if (w < 2) {
            f32x4 acc[4] = {};
            const us* A1 = ctx + (size_t)(b0 + l15) * HH + quad * 8;
            const us* B1 = wiR + (size_t)(c0 + l15) * HH + quad * 8;
#pragma unroll 4
            for (int kk = 0; kk < 16; ++kk) {
                bf16x8 a = ldb8_dev(A1 + kk * 32);
#pragma unroll
                for (int gg = 0; gg < 4; ++gg) {
                    bf16x8 bv = ldb8(B1 + (size_t)gg * HH * HH + kk * 32);
                    acc[gg] = __builtin_amdgcn_mfma_f32_16x16x32_bf16(a, bv, acc[gg], 0, 0, 0);
                }
            }
            const us* A2 = hcur + (size_t)(b0 + l15) * HH + quad * 8;
            const us* B2 = whD + (size_t)(c0 + l15) * HH + quad * 8;
#pragma unroll 4
            for (int kk = 0; kk < 16; ++kk) {
                bf16x8 a = ldb8_dev(A2 + kk * 32);
#pragma unroll
                for (int gg = 0; gg < 4; ++gg) {
                    bf16x8 bv = ldb8(B2 + (size_t)gg * HH * HH + kk * 32);
                    acc[gg] = __builtin_amdgcn_mfma_f32_16x16x32_bf16(a, bv, acc[gg], 0, 0, 0);
                }
            }
            us* hnxt = hdec + (size_t)((t + 1) & 1) * BB * HH;
            const float* dcur = din + (size_t)(t & 1) * BB;
#pragma unroll
            for (int r = 0; r < 4; ++r) {
                int b = b0 + quad * 4 + r;
                float dv = (t == 0) ? 0.f
                                    : __hip_atomic_load((const float*)&dcur[b], __ATOMIC_RELAXED,
                                                        __HIP_MEMORY_SCOPE_AGENT);
                float zi = acc[0][r] + biD[0] + dv * wlD[0];
                float zf = acc[1][r] + biD[1] + dv * wlD[1];
                float zg = acc[2][r] + biD[2] + dv * wlD[2];
                float zo = acc[3][r] + biD[3] + dv * wlD[3];
                float c_ = sigm(zf) * creg[r] + sigm(zi) * tanh_(zg);
                creg[r] = c_;
                st_pair_dev(&hnxt[(size_t)b * HH + c0 + l15], (unsigned)f2bf(sigm(zo) * tanh_(c_)),
                            lane);
            }
        }
        gsync_nf(flags, myflag, g * 16, 16, ++tgt);
    }
}

extern "C" void kernel_launch(void* const* d_in, const int* in_sizes, int n_in,
                              void* d_out, int out_size, void* d_ws, size_t ws_size,
                              hipStream_t stream) {
    const int* xs = (const int*)d_in[0];
    const int* argsort = (const int*)d_in[2];
    const float* enc_Wi = (const float*)d_in[3];
    const float* enc_Wh = (const float*)d_in[4];
    const float* enc_b = (const float*)d_in[5];
    const float* dec_Wi = (const float*)d_in[6];
    const float* dec_Wh = (const float*)d_in[7];
    const float* dec_b = (const float*)d_in[8];
    const float* w1 = (const float*)d_in[9];
    const float* w2 = (const float*)d_in[10];
    const float* vt = (const float*)d_in[11];
    float* out = (float*)d_out;
    char* ws = (char*)d_ws;

    hipMemsetAsync(ws, 0, 16384, stream);

    void* kargs[] = {&xs, &argsort, &enc_Wi, &enc_Wh, &enc_b, &dec_Wi, &dec_Wh, &dec_b,
                     &w1, &w2, &vt, &out, &ws};
    hipLaunchCooperativeKernel((void*)k_mega, dim3(256), dim3(512), kargs, 0, stream);

    (void)in_sizes; (void)n_in; (void)out_size; (void)ws_size;
}